// Round 7
// baseline (23.210 us; speedup 1.0000x reference)
//
#include <hip/hip_runtime.h>
#include <math.h>

// Geometry (fixed by the reference).
#define HS    2048            // hidden size (output columns)
#define DIN   2048            // input dim (reduction length)
#define RPS   16              // rows per slab
#define NSLAB (DIN / RPS)     // 128 slabs per matrix
#define NBLK1 1024            // 4 mats x 128 slabs x 2 column halves
#define NBLK2 64              // stage-2 blocks

// ---------------------------------------------------------------------------
// Algebra: cell = f*c0 + dot(i,c); dot(i,c) is a scalar broadcast and the
// mean/std normalization cancels constant shifts, so
//   h = o * tanh((f*c0 - mean(f*c0)) / (std(f*c0, ddof=1) + 1e-5)).
// The i and c gates (w_xi, w_hi, w_xc, w_hc, b_i, b_c) are dead.
//
// Stage 1: slab-streaming partial GEMV at 32 waves/CU.
//   Block b: mat = b>>8, rem = b&255, slab = rem>>1 (16 rows), ch = rem&1
//   (1024-col half). 512 threads: p = t>>8 (row phase), tc = t&255 (fixed
//   float4 column quad). Phase p accumulates rows r0+p, r0+p+2, ... (8 rows,
//   8 independent float4 loads, every wave-instruction 1 KB contiguous).
//   Phases joined by one 4 KB LDS add; threads 0..255 store the 4 KB
//   partial row. zp total 4 MB, pure overwrite (poison-proof), no atomics.
//   __launch_bounds__(512, 8) caps VGPR<=64 -> 8 waves/SIMD = 32 waves/CU.
// ---------------------------------------------------------------------------
__global__ __launch_bounds__(512, 8) void gemv_slab(
        const float* __restrict__ x,    const float* __restrict__ h0,
        const float* __restrict__ w_xf, const float* __restrict__ w_hf,
        const float* __restrict__ w_xo, const float* __restrict__ w_ho,
        float* __restrict__ zp /* [NBLK1][1024] */) {
    const int b    = blockIdx.x;
    const int t    = threadIdx.x;
    const int mat  = b >> 8;                 // 0:w_xf 1:w_hf 2:w_xo 3:w_ho
    const int rem  = b & 255;
    const int slab = rem >> 1;
    const int ch   = rem & 1;

    const float* W   = (mat == 0) ? w_xf : (mat == 1) ? w_hf
                     : (mat == 2) ? w_xo : w_ho;
    const float* vec = (mat & 1) ? h0 : x;

    const int r0 = slab * RPS;
    const int p  = t >> 8;                   // row phase 0/1 (waves 0-3 / 4-7)
    const int tc = t & 255;                  // fixed float4 column quad
    const float* wp = W + (size_t)(r0 + p) * HS + ch * 1024 + tc * 4;

    float4 a0 = make_float4(0.f, 0.f, 0.f, 0.f);
    float4 a1 = make_float4(0.f, 0.f, 0.f, 0.f);
#pragma unroll
    for (int k = 0; k < 8; k += 2) {
        const float  s0 = vec[r0 + p + 2 * k];          // wave-uniform
        const float  s1 = vec[r0 + p + 2 * k + 2];
        const float4 w0 = *reinterpret_cast<const float4*>(wp + (size_t)(2 * k) * HS);
        const float4 w1 = *reinterpret_cast<const float4*>(wp + (size_t)(2 * k + 2) * HS);
        a0.x = fmaf(s0, w0.x, a0.x);  a0.y = fmaf(s0, w0.y, a0.y);
        a0.z = fmaf(s0, w0.z, a0.z);  a0.w = fmaf(s0, w0.w, a0.w);
        a1.x = fmaf(s1, w1.x, a1.x);  a1.y = fmaf(s1, w1.y, a1.y);
        a1.z = fmaf(s1, w1.z, a1.z);  a1.w = fmaf(s1, w1.w, a1.w);
    }
    float4 a;
    a.x = a0.x + a1.x;  a.y = a0.y + a1.y;
    a.z = a0.z + a1.z;  a.w = a0.w + a1.w;

    __shared__ float4 lds[256];              // cross-phase join (4 KB)
    if (p == 1) lds[tc] = a;
    __syncthreads();
    if (p == 0) {
        const float4 o = lds[tc];
        a.x += o.x;  a.y += o.y;  a.z += o.z;  a.w += o.w;
        reinterpret_cast<float4*>(zp + (size_t)b * 1024)[tc] = a;
    }
}

// ---------------------------------------------------------------------------
// Stage 2 (unchanged from r6; zp layout identical): reduce 256 slab-partials
// per (gate, column) with float4 loads, sigmoid, then last-block ticket ->
// mean/std normalize -> output. atomicInc-wrap ticket selects exactly one
// block per call for ANY initial counter value (0xAA poison ok).
// ---------------------------------------------------------------------------
__global__ __launch_bounds__(256) void reduce_fin(
        const float* __restrict__ zp,
        const float* __restrict__ b_f, const float* __restrict__ b_o,
        const float* __restrict__ c0,  float* __restrict__ out,
        float* __restrict__ vbuf, float* __restrict__ obuf,
        unsigned* __restrict__ cnt) {
    const int t  = threadIdx.x;
    const int g  = blockIdx.x >> 5;          // 0 = f, 1 = o
    const int cg = blockIdx.x & 31;          // 64-col group
    const int fg = t & 15;                   // float4 quad within group
    const int ph = t >> 4;                   // slab phase 0..15

    __shared__ float4 part[4][16];
    __shared__ unsigned lastFlag;

    const int ch = cg >> 4;                  // column half of this group
    const int cw = (cg & 15) * 64 + fg * 4;  // offset within the half

    float4 acc0 = make_float4(0.f, 0.f, 0.f, 0.f);
    float4 acc1 = make_float4(0.f, 0.f, 0.f, 0.f);
#pragma unroll
    for (int k = 0; k < 8; ++k) {
        const int slab = ph + (k << 4);
#pragma unroll
        for (int m = 0; m < 2; ++m) {
            const int rr = ((g * 2 + m) * NSLAB + slab) * 2 + ch;
            const float4 p = *reinterpret_cast<const float4*>(
                zp + (size_t)rr * 1024 + cw);
            float4& a = m ? acc1 : acc0;
            a.x += p.x;  a.y += p.y;  a.z += p.z;  a.w += p.w;
        }
    }
    float4 s4;
    s4.x = acc0.x + acc1.x;  s4.y = acc0.y + acc1.y;
    s4.z = acc0.z + acc1.z;  s4.w = acc0.w + acc1.w;

    // reduce the 4 in-wave phases (lanes l, l^16, l^32 hold adjacent ph)
#pragma unroll
    for (int m = 16; m <= 32; m <<= 1) {
        s4.x += __shfl_xor(s4.x, m);
        s4.y += __shfl_xor(s4.y, m);
        s4.z += __shfl_xor(s4.z, m);
        s4.w += __shfl_xor(s4.w, m);
    }
    if ((t & 63) < 16) part[t >> 6][fg] = s4;
    __syncthreads();

    if (t < 16) {
        float4 z;
        z.x = (part[0][t].x + part[1][t].x) + (part[2][t].x + part[3][t].x);
        z.y = (part[0][t].y + part[1][t].y) + (part[2][t].y + part[3][t].y);
        z.z = (part[0][t].z + part[1][t].z) + (part[2][t].z + part[3][t].z);
        z.w = (part[0][t].w + part[1][t].w) + (part[2][t].w + part[3][t].w);
        const int col = cg * 64 + t * 4;
        if (g == 0) {
            const float4 bf = *reinterpret_cast<const float4*>(b_f + col);
            const float4 cv = *reinterpret_cast<const float4*>(c0 + col);
            float4 r;
            r.x = cv.x / (1.f + expf(-(z.x + bf.x)));
            r.y = cv.y / (1.f + expf(-(z.y + bf.y)));
            r.z = cv.z / (1.f + expf(-(z.z + bf.z)));
            r.w = cv.w / (1.f + expf(-(z.w + bf.w)));
            *reinterpret_cast<float4*>(vbuf + col) = r;   // v = sig(zf)*c0
        } else {
            const float4 bo = *reinterpret_cast<const float4*>(b_o + col);
            float4 r;
            r.x = 1.f / (1.f + expf(-(z.x + bo.x)));
            r.y = 1.f / (1.f + expf(-(z.y + bo.y)));
            r.z = 1.f / (1.f + expf(-(z.z + bo.z)));
            r.w = 1.f / (1.f + expf(-(z.w + bo.w)));
            *reinterpret_cast<float4*>(obuf + col) = r;   // o gate
        }
    }
    __syncthreads();

    // ---- last-block ticket (device scope; robust to any initial cnt) ----
    if (t == 0) {
        __threadfence();                          // release vbuf/obuf writes
        const unsigned old = atomicInc(cnt, NBLK2 - 1u);
        lastFlag = (old == NBLK2 - 2u);           // exactly one block per call
    }
    __syncthreads();
    if (!lastFlag) return;
    __threadfence();                              // acquire

    // ---- finalize: h = o * tanh((v - mean) / (std_ddof1 + 1e-5)) ----
    const int lane = t & 63;
    const int wv   = t >> 6;
    __shared__ float red[2][4];

    float v[8], og[8];
    float lsum = 0.f;
#pragma unroll
    for (int e = 0; e < 8; ++e) {
        const int j = t * 8 + e;
        v[e]  = vbuf[j];
        og[e] = obuf[j];
        lsum += v[e];
    }
#pragma unroll
    for (int s = 32; s > 0; s >>= 1) lsum += __shfl_down(lsum, s);
    if (lane == 0) red[0][wv] = lsum;
    __syncthreads();
    const float mean = (red[0][0] + red[0][1] + red[0][2] + red[0][3]) * (1.f / 2048.f);

    float lss = 0.f;
#pragma unroll
    for (int e = 0; e < 8; ++e) {
        const float d = v[e] - mean;
        lss += d * d;
    }
#pragma unroll
    for (int s = 32; s > 0; s >>= 1) lss += __shfl_down(lss, s);
    if (lane == 0) red[1][wv] = lss;
    __syncthreads();
    const float var = (red[1][0] + red[1][1] + red[1][2] + red[1][3]) * (1.f / 2047.f);
    const float inv = 1.f / (sqrtf(var) + 1e-5f);

#pragma unroll
    for (int e = 0; e < 8; ++e) {
        const int j = t * 8 + e;
        out[j] = og[e] * tanhf((v[e] - mean) * inv);
    }
}

extern "C" void kernel_launch(void* const* d_in, const int* in_sizes, int n_in,
                              void* d_out, int out_size, void* d_ws, size_t ws_size,
                              hipStream_t stream) {
    // setup_inputs order:
    // 0:x 1:w_xi 2:w_xf 3:w_xo 4:w_xc 5:w_hi 6:w_hf 7:w_ho 8:w_hc
    // 9:b_i 10:b_f 11:b_o 12:b_c 13:h0 14:c0
    const float* x    = (const float*)d_in[0];
    const float* w_xf = (const float*)d_in[2];
    const float* w_xo = (const float*)d_in[3];
    const float* w_hf = (const float*)d_in[6];
    const float* w_ho = (const float*)d_in[7];
    const float* b_f  = (const float*)d_in[10];
    const float* b_o  = (const float*)d_in[11];
    const float* h0   = (const float*)d_in[13];
    const float* c0   = (const float*)d_in[14];
    float* out = (float*)d_out;

    float* zp     = (float*)d_ws;                  // [1024][1024] fp32 = 4 MB
    float* vbuf   = zp + (size_t)NBLK1 * 1024;     // 2048 fp32
    float* obuf   = vbuf + HS;                     // 2048 fp32
    unsigned* cnt = (unsigned*)(obuf + HS);        // ticket (any init ok)

    gemv_slab<<<NBLK1, 512, 0, stream>>>(x, h0, w_xf, w_hf, w_xo, w_ho, zp);
    reduce_fin<<<NBLK2, 256, 0, stream>>>(zp, b_f, b_o, c0, out, vbuf, obuf, cnt);
}